// Round 5
// baseline (1835.964 us; speedup 1.0000x reference)
//
#include <hip/hip_runtime.h>

typedef __attribute__((ext_vector_type(8))) short bf16x8;   // 8 bf16 = 4 VGPRs
typedef __attribute__((ext_vector_type(4))) float f32x4;    // MFMA C/D

__device__ __forceinline__ float bf2f(unsigned short u){
    unsigned int v = ((unsigned int)u) << 16;
    return __builtin_bit_cast(float, v);
}
__device__ __forceinline__ unsigned short f2bf(float f){
    unsigned int u = __builtin_bit_cast(unsigned int, f);
    u += 0x7FFFu + ((u >> 16) & 1u);   // RTNE (no NaN inputs here)
    return (unsigned short)(u >> 16);
}

// ---- prep: W (K x 256) fp32 -> Wt (256 x K) bf16 (transposed) ----
__global__ void prep_wt(const float* __restrict__ W, unsigned short* __restrict__ Wt, int K){
    int k = blockIdx.x;
    int j = threadIdx.x;
    Wt[(size_t)j * K + k] = f2bf(W[(size_t)k * 256 + j]);
}

// ---- prep: x (b,m,d) fp32 -> Xt[b][d][m] bf16 ----
__global__ void prep_x(const float* __restrict__ x, unsigned short* __restrict__ Xt){
    int b = blockIdx.x;
    int t = threadIdx.x;
    #pragma unroll
    for (int it = 0; it < 8; it++){
        int o = it * 256 + t;          // o = d*32 + m
        int d = o >> 5, m = o & 31;
        Xt[(size_t)b * 2048 + o] = f2bf(x[(size_t)b * 2048 + m * 64 + d]);
    }
}

__global__ void init_out(float* __restrict__ out, const float* __restrict__ fcb){
    int i = blockIdx.x * 256 + threadIdx.x;
    if (i < 1024) out[i] = fcb[0];
}

// ---- fused CIN stage, Z-free formulation with AGPR-chained m-group accumulation ----
// Y[j][c] = sum_m x[c][m] * (sum_n W[(m,n)][j] * h[c][n])
// Per m-group (SB = NN/32 kt's): chain MFMAs into tmp[jt][ct] (AGPR, C-chained,
// B = RAW h fragment -> zero B-build VALU), then fold acc += xv[ct]*tmp once.
// Verified correct in round 2; round 2's only defect was __launch_bounds__(256,1)
// (1 wave/SIMD, latency-exposed). Measured VGPR_Count was 236 <= 256, so 2
// waves/SIMD fits: this version declares (256,2). LDS 45 KB -> 2 blocks/CU.
// Block: 128 c (2 batch elems), 4 waves, j in [64w, 64w+64). No main-loop barriers.
template<int NN, int LOG2NN, int KTOT, int JX, bool HAS_HOUT>
__global__ __launch_bounds__(256, 2) void cin_stage(
    const unsigned short* __restrict__ Xt,
    const unsigned short* __restrict__ Hin,
    const unsigned short* __restrict__ Wt,
    const float* __restrict__ bias,
    const float* __restrict__ fcW,      // pre-offset for this layer
    unsigned short* __restrict__ Hout,  // [b][d][n] bf16, n in [0,128); null if !HAS_HOUT
    float* __restrict__ out)
{
    constexpr int KT = KTOT / 32;
    constexpr int SB = NN / 32;                 // kt per m-group
    constexpr int XS = 40;                      // Xl row stride (shorts)
    constexpr int HS = (NN == 32) ? XS : 136;   // Hl row stride (272B: b128-aligned, balanced banks)

    __shared__ unsigned short smem[22528];      // 45056 B -> 2 blocks/CU
    unsigned short* const Xl = smem;                          // [128][40]  10240 B
    unsigned short* const Hl = (NN == 32) ? smem : (smem + 5120); // [128][136] 34816 B
    unsigned short* const Yl = smem + 5120;     // epilogue overlay [n:128][c pad 136]

    const int t    = threadIdx.x;
    const int lane = t & 63;
    const int w    = t >> 6;
    const int li   = lane & 15;
    const int lq   = lane >> 4;
    const int bpair = blockIdx.x;

    // ---- one-time staging of x (and h) into LDS, fully coalesced ----
    {
        const int c  = t >> 1;
        const int b  = bpair * 2 + (c >> 6);
        const int d  = c & 63;
        const int mh = (t & 1) << 4;            // 16 shorts per thread
        const uint4* xsrc = (const uint4*)(Xt + ((size_t)b << 11) + (d << 5) + mh);
        uint4 x0 = xsrc[0], x1 = xsrc[1];
        *(uint4*)(Xl + c * XS + mh)     = x0;
        *(uint4*)(Xl + c * XS + mh + 8) = x1;
        if (NN == 128){
            const int nh = (t & 1) << 6;        // 64 shorts per thread
            const uint4* hsrc = (const uint4*)(Hin + (size_t)((b << 6) + d) * 128 + nh);
            #pragma unroll
            for (int q = 0; q < 8; q++){
                uint4 hv = hsrc[q];
                *(uint4*)(Hl + c * HS + nh + q * 8) = hv;
            }
        }
    }
    __syncthreads();

    // A-fragments: lane reads Wt[j = w*64 + jt*16 + li][kt*32 + lq*8 .. +8)
    const unsigned short* wbase = Wt + (size_t)((w << 6) + li) * KTOT + (lq << 3);
    auto loadA = [&](int kt, bf16x8* A){
        const unsigned short* wk = wbase + (kt << 5);
        #pragma unroll
        for (int jt = 0; jt < 4; jt++)
            A[jt] = *(const bf16x8*)(wk + (size_t)jt * 16 * KTOT);
    };

    f32x4 acc[4][8];
    #pragma unroll
    for (int jt = 0; jt < 4; jt++)
        #pragma unroll
        for (int ct = 0; ct < 8; ct++)
            acc[jt][ct] = (f32x4){0.f, 0.f, 0.f, 0.f};

    const f32x4 fzero = (f32x4){0.f, 0.f, 0.f, 0.f};

    bf16x8 Acur[4];
    loadA(0, Acur);

    for (int m = 0; m < 32; m++){
        // per-lane x scalars for this m (broadcast across lq, 2-way banked: free)
        float xv[8];
        #pragma unroll
        for (int ct = 0; ct < 8; ct++)
            xv[ct] = bf2f(Xl[((ct << 4) + li) * XS + m]);

        f32x4 tmp[4][8];   // MFMA-only C-chain -> AGPRs
        #pragma unroll
        for (int s = 0; s < SB; s++){
            const int kt = m * SB + s;
            bf16x8 Anx[4];
            loadA(kt + 1 < KT ? kt + 1 : kt, Anx);   // prefetch next A (L2-resident)
            const int nb = s << 5;
            #pragma unroll
            for (int ct = 0; ct < 8; ct++){
                bf16x8 B = *(const bf16x8*)(Hl + ((ct << 4) + li) * HS + nb + (lq << 3));
                #pragma unroll
                for (int jt = 0; jt < 4; jt++){
                    tmp[jt][ct] = __builtin_amdgcn_mfma_f32_16x16x32_bf16(
                        Acur[jt], B, (s == 0) ? fzero : tmp[jt][ct], 0, 0, 0);
                }
            }
            #pragma unroll
            for (int jt = 0; jt < 4; jt++) Acur[jt] = Anx[jt];
        }

        // fold: acc += xv * tmp (once per m-group)
        #pragma unroll
        for (int jt = 0; jt < 4; jt++)
            #pragma unroll
            for (int ct = 0; ct < 8; ct++)
                #pragma unroll
                for (int r = 0; r < 4; r++)
                    acc[jt][ct][r] += xv[ct] * tmp[jt][ct][r];
    }

    if (HAS_HOUT) __syncthreads();   // Yl overlays Hl (NN==128): all waves done reading

    // epilogue: bias + relu; fc partial sums; stage h-half into Yl
    float pfc0 = 0.f, pfc1 = 0.f;
    #pragma unroll
    for (int jt = 0; jt < 4; jt++){
        const int jb = (w << 6) + (jt << 4) + (lq << 2);
        float bv[4], fv[4];
        #pragma unroll
        for (int r = 0; r < 4; r++){
            int j = jb + r;
            bv[r] = bias[j];
            fv[r] = (j < JX) ? fcW[j] : 0.f;
        }
        #pragma unroll
        for (int ct = 0; ct < 8; ct++){
            f32x4 f = acc[jt][ct];
            int c = (ct << 4) + li;
            float ps = 0.f;
            #pragma unroll
            for (int r = 0; r < 4; r++){
                float y = f[r] + bv[r];
                y = y > 0.f ? y : 0.f;
                ps += fv[r] * y;
                if (HAS_HOUT){
                    int j = jb + r;
                    if (j >= 128)
                        Yl[(j - 128) * 136 + c] = f2bf(y);
                }
            }
            if (ct < 4) pfc0 += ps; else pfc1 += ps;
        }
    }
    #pragma unroll
    for (int off = 32; off; off >>= 1){
        pfc0 += __shfl_xor(pfc0, off, 64);
        pfc1 += __shfl_xor(pfc1, off, 64);
    }
    if (lane == 0){
        atomicAdd(out + bpair * 2 + 0, pfc0);
        atomicAdd(out + bpair * 2 + 1, pfc1);
    }

    if (HAS_HOUT){
        __syncthreads();
        // cooperative store: Hout[(bpair*128 + c)*128 + n] = Yl[n][c]
        const int c  = t >> 1;
        const int nh = (t & 1) << 6;
        unsigned short* gdst = Hout + (size_t)(bpair * 128 + c) * 128 + nh;
        #pragma unroll
        for (int i8 = 0; i8 < 8; i8++){
            uint4 tv;
            unsigned short* tmp2 = (unsigned short*)&tv;
            #pragma unroll
            for (int q = 0; q < 8; q++)
                tmp2[q] = Yl[(nh + i8 * 8 + q) * 136 + c];
            *(uint4*)(gdst + i8 * 8) = tv;
        }
    }
}

extern "C" void kernel_launch(void* const* d_in, const int* in_sizes, int n_in,
                              void* d_out, int out_size, void* d_ws, size_t ws_size,
                              hipStream_t stream){
    const float* x   = (const float*)d_in[0];
    const float* W0  = (const float*)d_in[1];
    const float* b0  = (const float*)d_in[2];
    const float* W1  = (const float*)d_in[3];
    const float* b1  = (const float*)d_in[4];
    const float* W2  = (const float*)d_in[5];
    const float* b2  = (const float*)d_in[6];
    const float* fcW = (const float*)d_in[7];
    const float* fcb = (const float*)d_in[8];
    float* out = (float*)d_out;

    char* ws = (char*)d_ws;
    unsigned short* Xt  = (unsigned short*)(ws);             // 4 MB
    unsigned short* Wt0 = (unsigned short*)(ws + 4194304);   // 512 KB
    unsigned short* Wt1 = (unsigned short*)(ws + 4718592);   // 2 MB
    unsigned short* Wt2 = (unsigned short*)(ws + 6815744);   // 2 MB
    unsigned short* H0  = (unsigned short*)(ws + 8912896);   // 16 MB
    unsigned short* H1  = (unsigned short*)(ws + 25690112);  // 16 MB (end 42467328)

    prep_wt<<<1024, 256, 0, stream>>>(W0, Wt0, 1024);
    prep_wt<<<4096, 256, 0, stream>>>(W1, Wt1, 4096);
    prep_wt<<<4096, 256, 0, stream>>>(W2, Wt2, 4096);
    prep_x <<<1024, 256, 0, stream>>>(x, Xt);
    init_out<<<4, 256, 0, stream>>>(out, fcb);

    cin_stage< 32, 5, 1024, 128, true ><<<512, 256, 0, stream>>>(Xt, Xt, Wt0, b0, fcW,       H0, out);
    cin_stage<128, 7, 4096, 128, true ><<<512, 256, 0, stream>>>(Xt, H0, Wt1, b1, fcW + 128, H1, out);
    cin_stage<128, 7, 4096, 256, false><<<512, 256, 0, stream>>>(Xt, H1, Wt2, b2, fcW + 256, nullptr, out);
}

// Round 6
// 410.112 us; speedup vs baseline: 4.4767x; 4.4767x over previous
//
#include <hip/hip_runtime.h>

typedef __attribute__((ext_vector_type(8))) short bf16x8;   // 8 bf16 = 4 VGPRs
typedef __attribute__((ext_vector_type(4))) unsigned int u32x4;
typedef __attribute__((ext_vector_type(4))) float f32x4;    // MFMA C/D

__device__ __forceinline__ float bf2f(unsigned short u){
    unsigned int v = ((unsigned int)u) << 16;
    return __builtin_bit_cast(float, v);
}
__device__ __forceinline__ unsigned short f2bf(float f){
    unsigned int u = __builtin_bit_cast(unsigned int, f);
    u += 0x7FFFu + ((u >> 16) & 1u);   // RTNE (no NaN inputs here)
    return (unsigned short)(u >> 16);
}
// HW packed f32->bf16 RTNE (verified correct in round 3)
__device__ __forceinline__ unsigned int cvt_pk_bf16(float lo, float hi){
    unsigned int r;
    asm("v_cvt_pk_bf16_f32 %0, %1, %2" : "=v"(r) : "v"(lo), "v"(hi));
    return r;
}

// ---- prep: W (K x 256) fp32 -> Wt (256 x K) bf16 (transposed) ----
__global__ void prep_wt(const float* __restrict__ W, unsigned short* __restrict__ Wt, int K){
    int k = blockIdx.x;
    int j = threadIdx.x;
    Wt[(size_t)j * K + k] = f2bf(W[(size_t)k * 256 + j]);
}

// ---- prep: x (b,m,d) fp32 -> Xt[b][d][m] bf16 ----
__global__ void prep_x(const float* __restrict__ x, unsigned short* __restrict__ Xt){
    int b = blockIdx.x;
    int t = threadIdx.x;
    #pragma unroll
    for (int it = 0; it < 8; it++){
        int o = it * 256 + t;          // o = d*32 + m
        int d = o >> 5, m = o & 31;
        Xt[(size_t)b * 2048 + o] = f2bf(x[(size_t)b * 2048 + m * 64 + d]);
    }
}

__global__ void init_out(float* __restrict__ out, const float* __restrict__ fcb){
    int i = blockIdx.x * 256 + threadIdx.x;
    if (i < 1024) out[i] = fcb[0];
}

// ---- fused CIN stage: Z-free, s-outer/m-inner, h-frags hoisted to registers ----
// Y[j][c] = sum_{m,s} x[c][m] * ( W-frag(kt=m*SB+s) MFMA h-frag(s,ct) ).
// KEY: the h fragment address has NO m-dependence -> per s, the 8 raw h-frags
// are loaded ONCE into regs (Bh[8]) and reused across all 32 m. Main loop has
// zero LDS reads except 8 broadcast x scalars/m (transposed Xlt, dbl-buffered).
// B built in regs: unpack(2) + mul(2) + v_cvt_pk_bf16_f32(1) per u32.
// acc = pure MFMA C-chain (AGPR). ~220 unified regs -> 2 waves/SIMD.
// Block: 128 c (2 batch elems), 4 waves, j in [64w, 64w+64). No main-loop barriers.
template<int NN, int LOG2NN, int KTOT, int JX, bool HAS_HOUT>
__global__ __launch_bounds__(256, 2) void cin_stage(
    const unsigned short* __restrict__ Xt,
    const unsigned short* __restrict__ Hin,
    const unsigned short* __restrict__ Wt,
    const float* __restrict__ bias,
    const float* __restrict__ fcW,      // pre-offset for this layer
    unsigned short* __restrict__ Hout,  // [b][d][n] bf16, n in [0,128); null if !HAS_HOUT
    float* __restrict__ out)
{
    constexpr int SB  = NN / 32;                // s values (kt per m-group)
    constexpr int XTS = 136;                    // Xlt row stride (shorts)
    constexpr int HS  = (NN == 32) ? 40 : 136;  // Hl row stride

    __shared__ unsigned short smem[21760];      // 43520 B -> 2 blocks/CU
    unsigned short* const Xlt = smem;                  // [32][136] transposed x, 8704 B
    unsigned short* const Hl  = smem + 4352;           // [128][HS]
    unsigned short* const Yl  = smem + 4352;           // epilogue overlay [n:128][c pad 136]

    const int t    = threadIdx.x;
    const int lane = t & 63;
    const int w    = t >> 6;
    const int li   = lane & 15;
    const int lq   = lane >> 4;
    const int bpair = blockIdx.x;

    // ---- one-time staging: x transposed into Xlt; h (or x row-major) into Hl ----
    {
        const int c  = t >> 1;
        const int b  = bpair * 2 + (c >> 6);
        const int d  = c & 63;
        const int mh = (t & 1) << 4;            // 16 shorts (m-range) per thread
        const uint4* xsrc = (const uint4*)(Xt + ((size_t)b << 11) + (d << 5) + mh);
        uint4 x0 = xsrc[0], x1 = xsrc[1];
        const unsigned short* xs0 = (const unsigned short*)&x0;
        const unsigned short* xs1 = (const unsigned short*)&x1;
        #pragma unroll
        for (int q = 0; q < 8; q++) Xlt[(mh + q) * XTS + c]     = xs0[q];
        #pragma unroll
        for (int q = 0; q < 8; q++) Xlt[(mh + 8 + q) * XTS + c] = xs1[q];
        if (NN == 32){
            // stage 0: h == x, row-major [c][40]
            *(uint4*)(Hl + c * HS + mh)     = x0;
            *(uint4*)(Hl + c * HS + mh + 8) = x1;
        } else {
            const int nh = (t & 1) << 6;        // 64 shorts per thread
            const uint4* hsrc = (const uint4*)(Hin + (size_t)((b << 6) + d) * 128 + nh);
            #pragma unroll
            for (int q = 0; q < 8; q++){
                uint4 hv = hsrc[q];
                *(uint4*)(Hl + c * HS + nh + q * 8) = hv;
            }
        }
    }
    __syncthreads();

    // A-fragments: lane reads Wt[j = w*64 + jt*16 + li][kt*32 + lq*8 .. +8)
    const unsigned short* wbase = Wt + (size_t)((w << 6) + li) * KTOT + (lq << 3);
    auto loadA = [&](int kt, bf16x8* A){
        const unsigned short* wk = wbase + (kt << 5);
        #pragma unroll
        for (int jt = 0; jt < 4; jt++)
            A[jt] = *(const bf16x8*)(wk + (size_t)jt * 16 * KTOT);
    };

    f32x4 acc[4][8];   // pure MFMA C-chain -> AGPRs
    #pragma unroll
    for (int jt = 0; jt < 4; jt++)
        #pragma unroll
        for (int ct = 0; ct < 8; ct++)
            acc[jt][ct] = (f32x4){0.f, 0.f, 0.f, 0.f};

    for (int s = 0; s < SB; s++){
        const int nb = s << 5;
        // hoist the 8 raw h fragments for this s: the ONLY B-side LDS reads
        bf16x8 Bh[8];
        #pragma unroll
        for (int ct = 0; ct < 8; ct++)
            Bh[ct] = *(const bf16x8*)(Hl + ((ct << 4) + li) * HS + nb + (lq << 3));

        bf16x8 Acur[4];
        loadA(s, Acur);                 // kt = 0*SB + s
        float xv[8];
        #pragma unroll
        for (int ct = 0; ct < 8; ct++)
            xv[ct] = bf2f(Xlt[(ct << 4) + li]);   // m = 0

        for (int m = 0; m < 32; m++){
            // prefetch next A (L2-resident) and next x scalars
            const int mn  = (m + 1 < 32) ? m + 1 : 31;
            const int ktn = (m + 1 < 32) ? (m + 1) * SB + s
                           : ((s + 1 < SB) ? (s + 1) : m * SB + s);
            bf16x8 Anx[4];
            loadA(ktn, Anx);
            float xvn[8];
            #pragma unroll
            for (int ct = 0; ct < 8; ct++)
                xvn[ct] = bf2f(Xlt[mn * XTS + (ct << 4) + li]);

            #pragma unroll
            for (int ct = 0; ct < 8; ct++){
                const u32x4 hw = __builtin_bit_cast(u32x4, Bh[ct]);
                const float xf = xv[ct];
                u32x4 bw;
                #pragma unroll
                for (int q = 0; q < 4; q++){
                    float flo = __builtin_bit_cast(float, hw[q] << 16);
                    float fhi = __builtin_bit_cast(float, hw[q] & 0xffff0000u);
                    bw[q] = cvt_pk_bf16(xf * flo, xf * fhi);
                }
                const bf16x8 B = __builtin_bit_cast(bf16x8, bw);
                #pragma unroll
                for (int jt = 0; jt < 4; jt++)
                    acc[jt][ct] = __builtin_amdgcn_mfma_f32_16x16x32_bf16(
                        Acur[jt], B, acc[jt][ct], 0, 0, 0);
            }
            #pragma unroll
            for (int jt = 0; jt < 4; jt++) Acur[jt] = Anx[jt];
            #pragma unroll
            for (int ct = 0; ct < 8; ct++) xv[ct] = xvn[ct];
        }
    }

    if (HAS_HOUT) __syncthreads();   // Yl overlays Hl: all waves done reading

    // epilogue: bias + relu; fc partial sums; stage h-half into Yl
    float pfc0 = 0.f, pfc1 = 0.f;
    #pragma unroll
    for (int jt = 0; jt < 4; jt++){
        const int jb = (w << 6) + (jt << 4) + (lq << 2);
        float bv[4], fv[4];
        #pragma unroll
        for (int r = 0; r < 4; r++){
            int j = jb + r;
            bv[r] = bias[j];
            fv[r] = (j < JX) ? fcW[j] : 0.f;
        }
        #pragma unroll
        for (int ct = 0; ct < 8; ct++){
            f32x4 f = acc[jt][ct];
            int c = (ct << 4) + li;
            float ps = 0.f;
            #pragma unroll
            for (int r = 0; r < 4; r++){
                float y = f[r] + bv[r];
                y = y > 0.f ? y : 0.f;
                ps += fv[r] * y;
                if (HAS_HOUT){
                    int j = jb + r;
                    if (j >= 128)
                        Yl[(j - 128) * 136 + c] = f2bf(y);
                }
            }
            if (ct < 4) pfc0 += ps; else pfc1 += ps;
        }
    }
    #pragma unroll
    for (int off = 32; off; off >>= 1){
        pfc0 += __shfl_xor(pfc0, off, 64);
        pfc1 += __shfl_xor(pfc1, off, 64);
    }
    if (lane == 0){
        atomicAdd(out + bpair * 2 + 0, pfc0);
        atomicAdd(out + bpair * 2 + 1, pfc1);
    }

    if (HAS_HOUT){
        __syncthreads();
        // cooperative store: Hout[(bpair*128 + c)*128 + n] = Yl[n][c]
        const int c  = t >> 1;
        const int nh = (t & 1) << 6;
        unsigned short* gdst = Hout + (size_t)(bpair * 128 + c) * 128 + nh;
        #pragma unroll
        for (int i8 = 0; i8 < 8; i8++){
            uint4 tv;
            unsigned short* tmp2 = (unsigned short*)&tv;
            #pragma unroll
            for (int q = 0; q < 8; q++)
                tmp2[q] = Yl[(nh + i8 * 8 + q) * 136 + c];
            *(uint4*)(gdst + i8 * 8) = tv;
        }
    }
}

extern "C" void kernel_launch(void* const* d_in, const int* in_sizes, int n_in,
                              void* d_out, int out_size, void* d_ws, size_t ws_size,
                              hipStream_t stream){
    const float* x   = (const float*)d_in[0];
    const float* W0  = (const float*)d_in[1];
    const float* b0  = (const float*)d_in[2];
    const float* W1  = (const float*)d_in[3];
    const float* b1  = (const float*)d_in[4];
    const float* W2  = (const float*)d_in[5];
    const float* b2  = (const float*)d_in[6];
    const float* fcW = (const float*)d_in[7];
    const float* fcb = (const float*)d_in[8];
    float* out = (float*)d_out;

    char* ws = (char*)d_ws;
    unsigned short* Xt  = (unsigned short*)(ws);             // 4 MB
    unsigned short* Wt0 = (unsigned short*)(ws + 4194304);   // 512 KB
    unsigned short* Wt1 = (unsigned short*)(ws + 4718592);   // 2 MB
    unsigned short* Wt2 = (unsigned short*)(ws + 6815744);   // 2 MB
    unsigned short* H0  = (unsigned short*)(ws + 8912896);   // 16 MB
    unsigned short* H1  = (unsigned short*)(ws + 25690112);  // 16 MB (end 42467328)

    prep_wt<<<1024, 256, 0, stream>>>(W0, Wt0, 1024);
    prep_wt<<<4096, 256, 0, stream>>>(W1, Wt1, 4096);
    prep_wt<<<4096, 256, 0, stream>>>(W2, Wt2, 4096);
    prep_x <<<1024, 256, 0, stream>>>(x, Xt);
    init_out<<<4, 256, 0, stream>>>(out, fcb);

    cin_stage< 32, 5, 1024, 128, true ><<<512, 256, 0, stream>>>(Xt, Xt, Wt0, b0, fcW,       H0, out);
    cin_stage<128, 7, 4096, 128, true ><<<512, 256, 0, stream>>>(Xt, H0, Wt1, b1, fcW + 128, H1, out);
    cin_stage<128, 7, 4096, 256, false><<<512, 256, 0, stream>>>(Xt, H1, Wt2, b2, fcW + 256, nullptr, out);
}